// Round 1
// baseline (300.855 us; speedup 1.0000x reference)
//
#include <hip/hip_runtime.h>
#include <hip/hip_bf16.h>

// Problem constants
#define BATCH     512
#define IMG       128
#define PS        8
#define GRID_P    16      // IMG/PS
#define NP        256     // GRID_P*GRID_P
#define C         128     // BOND_DIM
#define R         64      // CP_RANK
#define E         512     // EMBED_DIM

// ---------------------------------------------------------------------------
// Kernel 1: patchify + patch embed + pos add
//   h0[b, p, c] = sum_k patch(b,p,k) * Wp[k,c] + bp[c] + pos[p,c]
// block = (b, gy): one image-row of 16 patches. 256 threads = 128 c x 2 halves
// ---------------------------------------------------------------------------
__global__ __launch_bounds__(256) void patch_embed_kernel(
    const float* __restrict__ x,     // (B,1,128,128)
    const float* __restrict__ Wp,    // (64,128)
    const float* __restrict__ bp,    // (128)
    const float* __restrict__ pos,   // (1,256,128)
    float* __restrict__ h0)          // (B,256,128)
{
    __shared__ __align__(16) float pix[PS * IMG];   // 8 rows x 128 cols = 4 KB
    const int bi = blockIdx.x;
    const int b  = bi >> 4;
    const int gy = bi & 15;
    const int t  = threadIdx.x;

    // cooperative load of 8 pixel rows (1024 floats) via float4
    {
        const float4* src = (const float4*)(x + ((size_t)b * IMG + gy * PS) * IMG);
        ((float4*)pix)[t] = src[t];
    }
    __syncthreads();

    const int c    = t & 127;
    const int half = t >> 7;          // which 8 gx's this thread owns

    float acc[8];
#pragma unroll
    for (int g = 0; g < 8; ++g) {
        const int gx = half * 8 + g;
        acc[g] = bp[c] + pos[(gy * GRID_P + gx) * C + c];
    }

    for (int py = 0; py < PS; ++py) {
#pragma unroll
        for (int px0 = 0; px0 < PS; px0 += 4) {
            const int k0 = py * PS + px0;
            const float w0 = Wp[(k0 + 0) * C + c];
            const float w1 = Wp[(k0 + 1) * C + c];
            const float w2 = Wp[(k0 + 2) * C + c];
            const float w3 = Wp[(k0 + 3) * C + c];
#pragma unroll
            for (int g = 0; g < 8; ++g) {
                const int gx = half * 8 + g;
                const float4 p4 = *((const float4*)(pix + py * IMG + gx * PS + px0));
                acc[g] += p4.x * w0 + p4.y * w1 + p4.z * w2 + p4.w * w3;
            }
        }
    }

#pragma unroll
    for (int g = 0; g < 8; ++g) {
        const int gx = half * 8 + g;
        h0[((size_t)b * NP + gy * GRID_P + gx) * C + c] = acc[g];
    }
}

// ---------------------------------------------------------------------------
// Kernel 2 (templated per level): quad-group + CP contraction
//   u[b,n,q,r] = sum_c x[b,n,q,c] * f[n,q,c,r]
//   p[b,n,r]   = prod_q u[b,n,q,r]
//   out[b,n,c] = sum_r p[b,n,r] * o[n,r,c]
// block = (node n, chunk of BCHUNK batches), processed in tiles of TB=16.
// 256 threads. f is re-read per tile (L2-resident) but amortized over 16 b.
// ---------------------------------------------------------------------------
template<int NN, int GIN, int BCHUNK>
__global__ __launch_bounds__(256) void cp_level_kernel(
    const float* __restrict__ hin,   // (B, GIN*GIN, C)
    const float* __restrict__ f,     // (NN, 4, C, R)
    const float* __restrict__ o,     // (NN, R, C)
    float* __restrict__ hout)        // (B, NN, C)
{
    constexpr int TB = 16;
    constexpr int G2 = GIN / 2;
    constexpr int NIN = GIN * GIN;
    constexpr int XS = 132;          // padded row stride (floats): 2-way banks, 16B aligned

    __shared__ __align__(16) float xs[4 * TB * XS];  // 33.8 KB, rows = (q*16+b)
    __shared__ __align__(16) float us[4 * TB * R];   // 16 KB
    __shared__ __align__(16) float ps[TB * R];       // 4 KB

    const int bi = blockIdx.x;
    const int n  = bi % NN;
    const int b0 = (bi / NN) * BCHUNK;
    const int y1 = n / G2, x1 = n % G2;
    const int t    = threadIdx.x;
    const int wave = t >> 6;         // = q in u-phase
    const int lane = t & 63;         // = r in u-phase

    int pidx[4];
#pragma unroll
    for (int q = 0; q < 4; ++q) {
        const int y0 = q >> 1, x0 = q & 1;
        pidx[q] = (2 * y1 + y0) * GIN + (2 * x1 + x0);
    }

    for (int tile = 0; tile < BCHUNK / TB; ++tile) {
        const int bt0 = b0 + tile * TB;

        // ---- load x tile: 64 rows (q,b) of 128 floats, 4 threads per row ----
        {
            const int row = t >> 2;          // 0..63
            const int j   = t & 3;
            const int q   = row >> 4;
            const int bb  = row & 15;
            const float* src = hin + ((size_t)(bt0 + bb) * NIN + pidx[q]) * C + j * 32;
            float* dst = xs + row * XS + j * 32;
#pragma unroll
            for (int i = 0; i < 8; ++i) {
                *((float4*)(dst + i * 4)) = *((const float4*)(src + i * 4));
            }
        }
        __syncthreads();

        // ---- u-phase: wave = q, lane = r; 16 batch accumulators ----
        {
            const int q = wave, r = lane;
            float acc[TB];
#pragma unroll
            for (int b = 0; b < TB; ++b) acc[b] = 0.f;
            const float* fq = f + ((size_t)(n * 4 + q) * C) * R + r;
            for (int c0 = 0; c0 < C; c0 += 4) {
                const float f0 = fq[(c0 + 0) * R];
                const float f1 = fq[(c0 + 1) * R];
                const float f2 = fq[(c0 + 2) * R];
                const float f3 = fq[(c0 + 3) * R];
#pragma unroll
                for (int b = 0; b < TB; ++b) {
                    const float4 xv = *((const float4*)(xs + (q * TB + b) * XS + c0));
                    acc[b] += xv.x * f0 + xv.y * f1 + xv.z * f2 + xv.w * f3;
                }
            }
#pragma unroll
            for (int b = 0; b < TB; ++b) us[(q * TB + b) * R + r] = acc[b];
        }
        __syncthreads();

        // ---- p-phase: product over 4 quadrants, 1024 (b,r) pairs ----
#pragma unroll
        for (int k = 0; k < (TB * R) / 256; ++k) {
            const int idx = t + 256 * k;
            const int b = idx >> 6, r = idx & 63;
            ps[idx] = us[(0 * TB + b) * R + r] * us[(1 * TB + b) * R + r]
                    * us[(2 * TB + b) * R + r] * us[(3 * TB + b) * R + r];
        }
        __syncthreads();

        // ---- o-phase: out[b,c] = sum_r p[b,r]*o[n,r,c]; thread = (c, 8 b's) ----
        {
            const int c  = t & 127;
            const int bg = t >> 7;
            float acc[8];
#pragma unroll
            for (int i = 0; i < 8; ++i) acc[i] = 0.f;
            const float* oc = o + (size_t)n * R * C + c;
            for (int r0 = 0; r0 < R; r0 += 4) {
                const float o0 = oc[(r0 + 0) * C];
                const float o1 = oc[(r0 + 1) * C];
                const float o2 = oc[(r0 + 2) * C];
                const float o3 = oc[(r0 + 3) * C];
#pragma unroll
                for (int i = 0; i < 8; ++i) {
                    const int b = bg * 8 + i;
                    const float4 pv = *((const float4*)(ps + b * R + r0));
                    acc[i] += pv.x * o0 + pv.y * o1 + pv.z * o2 + pv.w * o3;
                }
            }
#pragma unroll
            for (int i = 0; i < 8; ++i) {
                const int b = bg * 8 + i;
                hout[((size_t)(bt0 + b) * NN + n) * C + c] = acc[i];
            }
        }
        __syncthreads();
    }
}

// ---------------------------------------------------------------------------
// Kernel 3: LayerNorm + head GEMV + L2 normalize. block = one batch row.
// ---------------------------------------------------------------------------
__global__ __launch_bounds__(256) void head_kernel(
    const float* __restrict__ h,     // (B, 1, 128)
    const float* __restrict__ gamma, const float* __restrict__ beta,
    const float* __restrict__ Wh,    // (128, 512)
    const float* __restrict__ bh,    // (512)
    float* __restrict__ out)         // (B, 512)
{
    const int b = blockIdx.x;
    const int t = threadIdx.x;
    const int lane = t & 63, wave = t >> 6;
    __shared__ __align__(16) float hn[C];
    __shared__ float red1[4], red2[4], red3[4];

    float v = 0.f;
    if (t < C) v = h[(size_t)b * C + t];
    float s = v, ss = v * v;
#pragma unroll
    for (int off = 32; off >= 1; off >>= 1) {
        s  += __shfl_down(s, off);
        ss += __shfl_down(ss, off);
    }
    if (lane == 0) { red1[wave] = s; red2[wave] = ss; }
    __syncthreads();
    const float sum   = red1[0] + red1[1] + red1[2] + red1[3];
    const float sumsq = red2[0] + red2[1] + red2[2] + red2[3];
    const float mu   = sum * (1.f / C);
    const float var  = sumsq * (1.f / C) - mu * mu;
    const float rstd = rsqrtf(var + 1e-5f);
    if (t < C) hn[t] = (v - mu) * rstd * gamma[t] + beta[t];
    __syncthreads();

    float acc0 = bh[t], acc1 = bh[t + 256];
    for (int c0 = 0; c0 < C; c0 += 4) {
        const float4 hv = *((const float4*)(hn + c0));
        const float* w  = Wh + (size_t)c0 * E + t;
        acc0 += hv.x * w[0] + hv.y * w[E] + hv.z * w[2 * E] + hv.w * w[3 * E];
        const float* w2 = w + 256;
        acc1 += hv.x * w2[0] + hv.y * w2[E] + hv.z * w2[2 * E] + hv.w * w2[3 * E];
    }

    float sq = acc0 * acc0 + acc1 * acc1;
#pragma unroll
    for (int off = 32; off >= 1; off >>= 1) sq += __shfl_down(sq, off);
    if (lane == 0) red3[wave] = sq;
    __syncthreads();
    float nrm = sqrtf(red3[0] + red3[1] + red3[2] + red3[3]);
    nrm = fmaxf(nrm, 1e-12f);
    const float inv = 1.f / nrm;
    out[(size_t)b * E + t]       = acc0 * inv;
    out[(size_t)b * E + t + 256] = acc1 * inv;
}

// ---------------------------------------------------------------------------
extern "C" void kernel_launch(void* const* d_in, const int* in_sizes, int n_in,
                              void* d_out, int out_size, void* d_ws, size_t ws_size,
                              hipStream_t stream) {
    const float* x     = (const float*)d_in[0];
    const float* Wp    = (const float*)d_in[1];
    const float* bp    = (const float*)d_in[2];
    const float* pos   = (const float*)d_in[3];
    const float* gamma = (const float*)d_in[4];
    const float* beta  = (const float*)d_in[5];
    const float* Wh    = (const float*)d_in[6];
    const float* bh    = (const float*)d_in[7];
    const float* f0    = (const float*)d_in[8];
    const float* o0    = (const float*)d_in[9];
    const float* f1    = (const float*)d_in[10];
    const float* o1    = (const float*)d_in[11];
    const float* f2    = (const float*)d_in[12];
    const float* o2    = (const float*)d_in[13];
    const float* f3    = (const float*)d_in[14];
    const float* o3    = (const float*)d_in[15];
    float* out = (float*)d_out;

    float* h0 = (float*)d_ws;                      // (512,256,128) = 64 MiB
    float* h1 = h0 + (size_t)BATCH * NP * C;       // (512, 64,128) = 16 MiB
    float* h2 = h1 + (size_t)BATCH * 64 * C;       // (512, 16,128) =  4 MiB
    float* h3 = h2 + (size_t)BATCH * 16 * C;       // (512,  4,128) =  1 MiB
    float* h4 = h3 + (size_t)BATCH * 4 * C;        // (512,  1,128) = 256 KiB

    patch_embed_kernel<<<BATCH * GRID_P, 256, 0, stream>>>(x, Wp, bp, pos, h0);

    cp_level_kernel<64, 16, 64><<<64 * (BATCH / 64), 256, 0, stream>>>(h0, f0, o0, h1);
    cp_level_kernel<16,  8, 16><<<16 * (BATCH / 16), 256, 0, stream>>>(h1, f1, o1, h2);
    cp_level_kernel< 4,  4, 16><<< 4 * (BATCH / 16), 256, 0, stream>>>(h2, f2, o2, h3);
    cp_level_kernel< 1,  2, 16><<< 1 * (BATCH / 16), 256, 0, stream>>>(h3, f3, o3, h4);

    head_kernel<<<BATCH, 256, 0, stream>>>(h4, gamma, beta, Wh, bh, out);
}